// Round 3
// baseline (39026.019 us; speedup 1.0000x reference)
//
#include <hip/hip_runtime.h>
#include <hip/hip_bf16.h>
#include <math.h>

#define B_   16
#define L_   512
#define D_   768
#define H_   12
#define KD_  64
#define F_   3072
#define NL_  12
#define NC_  4
#define NTOK (B_*L_)          // 8192
#define ND   ((size_t)NTOK*D_) // 6291456 floats

// ---------------------------------------------------------------------------
// Generic fp32 GEMM: C[rows x M] = act(A[rows x K] @ W[K x M] + bias (+ residual))
// BM=BN=64, BK=16, 256 threads, 4x4 per thread. Guards on rows and M.
// act: 0=none, 1=gelu(exact), 2=tanh
// ---------------------------------------------------------------------------
__global__ __launch_bounds__(256) void gemm_kernel(
    const float* __restrict__ A, const float* __restrict__ W,
    const float* __restrict__ bias, const float* __restrict__ residual,
    float* __restrict__ C, int rows, int K, int M, int act)
{
    // +4 pad keeps 16B alignment for float4 LDS reads (272B row stride)
    __shared__ __align__(16) float As[16][68];
    __shared__ __align__(16) float Bs[16][68];
    int tid = threadIdx.x;
    int tx = tid & 15, ty = tid >> 4;
    int r0 = blockIdx.y * 64;
    int c0 = blockIdx.x * 64;

    int aRow = tid >> 2;          // 0..63
    int aK   = (tid & 3) * 4;     // 0,4,8,12
    int bK   = tid >> 4;          // 0..15
    int bCol = (tid & 15) * 4;    // 0..60

    float acc[4][4] = {};

    for (int k0 = 0; k0 < K; k0 += 16) {
        float4 av = make_float4(0.f,0.f,0.f,0.f);
        if (r0 + aRow < rows)
            av = *reinterpret_cast<const float4*>(&A[(size_t)(r0 + aRow) * K + k0 + aK]);
        As[aK+0][aRow] = av.x; As[aK+1][aRow] = av.y;
        As[aK+2][aRow] = av.z; As[aK+3][aRow] = av.w;

        float4 bv;
        if (c0 + bCol + 3 < M) {
            bv = *reinterpret_cast<const float4*>(&W[(size_t)(k0 + bK) * M + c0 + bCol]);
        } else {
            float tmp[4];
            #pragma unroll
            for (int u = 0; u < 4; ++u) {
                int c = c0 + bCol + u;
                tmp[u] = (c < M) ? W[(size_t)(k0 + bK) * M + c] : 0.f;
            }
            bv = make_float4(tmp[0], tmp[1], tmp[2], tmp[3]);
        }
        Bs[bK][bCol+0] = bv.x; Bs[bK][bCol+1] = bv.y;
        Bs[bK][bCol+2] = bv.z; Bs[bK][bCol+3] = bv.w;
        __syncthreads();

        #pragma unroll
        for (int k = 0; k < 16; ++k) {
            float4 a4 = *reinterpret_cast<const float4*>(&As[k][ty*4]);
            float4 b4 = *reinterpret_cast<const float4*>(&Bs[k][tx*4]);
            float av_[4] = {a4.x, a4.y, a4.z, a4.w};
            float bv_[4] = {b4.x, b4.y, b4.z, b4.w};
            #pragma unroll
            for (int ii = 0; ii < 4; ++ii)
                #pragma unroll
                for (int jj = 0; jj < 4; ++jj)
                    acc[ii][jj] += av_[ii] * bv_[jj];
        }
        __syncthreads();
    }

    #pragma unroll
    for (int ii = 0; ii < 4; ++ii) {
        int r = r0 + ty*4 + ii;
        if (r >= rows) continue;
        #pragma unroll
        for (int jj = 0; jj < 4; ++jj) {
            int c = c0 + tx*4 + jj;
            if (c >= M) continue;
            float v = acc[ii][jj] + bias[c];
            if (residual) v += residual[(size_t)r * M + c];
            if (act == 1)      v = 0.5f * v * (1.f + erff(v * 0.70710678118654752f));
            else if (act == 2) v = tanhf(v);
            C[(size_t)r * M + c] = v;
        }
    }
}

static void launch_gemm(const float* A, const float* W, const float* bias,
                        const float* residual, float* C, int rows, int K, int M,
                        int act, hipStream_t stream)
{
    dim3 grid((M + 63) / 64, (rows + 63) / 64);
    gemm_kernel<<<grid, dim3(256), 0, stream>>>(A, W, bias, residual, C, rows, K, M, act);
}

// ---------------------------------------------------------------------------
// Embedding sum (word + pos + type0), one block per token
// ---------------------------------------------------------------------------
__global__ __launch_bounds__(256) void embed_kernel(
    const int* __restrict__ ids, const float* __restrict__ we,
    const float* __restrict__ pe, const float* __restrict__ te,
    float* __restrict__ out)
{
    int row = blockIdx.x;
    int s = row & (L_ - 1);
    int id = ids[row];
    const float* w = we + (size_t)id * D_;
    const float* p = pe + (size_t)s * D_;
    float* o = out + (size_t)row * D_;
    for (int d = threadIdx.x; d < D_; d += 256)
        o[d] = w[d] + p[d] + te[d];
}

// ---------------------------------------------------------------------------
// LayerNorm over D=768, one block (256 thr) per row. eps = 1e-12
// ---------------------------------------------------------------------------
__global__ __launch_bounds__(256) void ln_kernel(
    const float* __restrict__ X, const float* __restrict__ w,
    const float* __restrict__ b, float* __restrict__ out)
{
    __shared__ float red[256];
    int row = blockIdx.x, tid = threadIdx.x;
    const float* x = X + (size_t)row * D_;
    float v[3];
    float s = 0.f;
    #pragma unroll
    for (int u = 0; u < 3; ++u) { v[u] = x[tid + u*256]; s += v[u]; }
    red[tid] = s; __syncthreads();
    for (int off = 128; off; off >>= 1) {
        if (tid < off) red[tid] += red[tid + off];
        __syncthreads();
    }
    float mu = red[0] * (1.f / D_);
    __syncthreads();
    float s2 = 0.f;
    #pragma unroll
    for (int u = 0; u < 3; ++u) { float d = v[u] - mu; s2 += d * d; }
    red[tid] = s2; __syncthreads();
    for (int off = 128; off; off >>= 1) {
        if (tid < off) red[tid] += red[tid + off];
        __syncthreads();
    }
    float var = red[0] * (1.f / D_);
    float inv = rsqrtf(var + 1e-12f);
    float* o = out + (size_t)row * D_;
    #pragma unroll
    for (int u = 0; u < 3; ++u) {
        int d = tid + u*256;
        o[d] = (v[u] - mu) * inv * w[d] + b[d];
    }
}

// ---------------------------------------------------------------------------
// Attention: one block per (b, head, 8 query rows). L=512 scores fit in LDS,
// so full (non-online) masked softmax. K/V chunks staged in LDS (stride 65).
// q,k,v layout: [b*L + s][hh*64 + d] (N x 768). out same layout.
// ---------------------------------------------------------------------------
__global__ __launch_bounds__(256) void attn_kernel(
    const float* __restrict__ q, const float* __restrict__ k,
    const float* __restrict__ v, const float* __restrict__ am,
    float* __restrict__ out)
{
    __shared__ float qs[8][64];
    __shared__ float ks[64*65];     // aliased as part[4][8][64] in the epilogue
    __shared__ float ps[8][512];
    __shared__ float ams[512];
    __shared__ float red[256];

    int tid = threadIdx.x;
    int i0 = blockIdx.x * 8;
    int hh = blockIdx.y;
    int b  = blockIdx.z;
    size_t base = (size_t)b * L_ * D_ + hh * 64;

    for (int u = tid; u < 8*64; u += 256) {
        int r = u >> 6, d = u & 63;
        qs[r][d] = q[base + (size_t)(i0 + r) * D_ + d];
    }
    for (int u = tid; u < L_; u += 256) ams[u] = am[b * L_ + u];
    __syncthreads();

    const float scale = 0.125f;  // 1/sqrt(64)
    int r  = tid >> 5;   // 0..7
    int jj = tid & 31;   // 0..31

    // phase 1: scores
    for (int c = 0; c < 8; ++c) {
        int j0 = c * 64;
        for (int u = tid; u < 64*64; u += 256) {
            int j = u >> 6, d = u & 63;
            ks[j*65 + d] = k[base + (size_t)(j0 + j) * D_ + d];
        }
        __syncthreads();
        #pragma unroll
        for (int t = 0; t < 2; ++t) {
            int j = jj + t*32;
            float acc = 0.f;
            #pragma unroll
            for (int d = 0; d < 64; ++d) acc += qs[r][d] * ks[j*65 + d];
            ps[r][j0 + j] = acc * scale;
        }
        __syncthreads();
    }

    // phase 2: masked softmax per row (exact reference semantics)
    for (int rr = 0; rr < 8; ++rr) {
        float m0 = ams[tid], m1 = ams[tid + 256];
        float mv0 = ps[rr][tid] * m0;
        float mv1 = ps[rr][tid + 256] * m1;
        red[tid] = fmaxf(mv0, mv1); __syncthreads();
        for (int off = 128; off; off >>= 1) {
            if (tid < off) red[tid] = fmaxf(red[tid], red[tid + off]);
            __syncthreads();
        }
        float mx = red[0];
        __syncthreads();
        float e0 = expf(mv0 - mx) * m0;
        float e1 = expf(mv1 - mx) * m1;
        red[tid] = e0 + e1; __syncthreads();
        for (int off = 128; off; off >>= 1) {
            if (tid < off) red[tid] += red[tid + off];
            __syncthreads();
        }
        float ssum = red[0];
        if (ssum == 0.f) ssum = 1.f;
        float inv = 1.f / ssum;
        __syncthreads();
        ps[rr][tid]       = e0 * inv;
        ps[rr][tid + 256] = e1 * inv;
        __syncthreads();
    }

    // phase 3: O = P @ V
    int d = tid & 63, g = tid >> 6;
    float facc[8] = {};
    for (int c = 0; c < 8; ++c) {
        int j0 = c * 64;
        for (int u = tid; u < 64*64; u += 256) {
            int j = u >> 6, dd = u & 63;
            ks[j*65 + dd] = v[base + (size_t)(j0 + j) * D_ + dd];
        }
        __syncthreads();
        #pragma unroll
        for (int rr = 0; rr < 8; ++rr) {
            float a = 0.f;
            #pragma unroll
            for (int u = 0; u < 16; ++u) {
                int j = g*16 + u;
                a += ps[rr][j0 + j] * ks[j*65 + d];
            }
            facc[rr] += a;
        }
        __syncthreads();
    }
    float* part = ks;  // [4][8][64]
    #pragma unroll
    for (int rr = 0; rr < 8; ++rr) part[g*512 + rr*64 + d] = facc[rr];
    __syncthreads();
    for (int u = tid; u < 512; u += 256) {
        int rr = u >> 6, dd = u & 63;
        float s = part[u] + part[512 + u] + part[1024 + u] + part[1536 + u];
        out[((size_t)(b * L_ + i0 + rr)) * D_ + hh*64 + dd] = s;
    }
}

// ---------------------------------------------------------------------------
// Mixup: per (b,i): over all 12 heads, softmax(q_i . k[mix[b]]^T * scale)
// masked by attention_mask[mix[b]]; cross_sim = max over heads; masked argmax
// over interior j (ties -> larger j, matching rank-based masked_argmax).
// Positions: i==0 -> 0, i==L-1 -> L-1 (cls/sep masks), else interior.
// ---------------------------------------------------------------------------
__global__ __launch_bounds__(256) void mixup_kernel(
    const float* __restrict__ q, const float* __restrict__ k,
    const float* __restrict__ am, const int* __restrict__ mix,
    int* __restrict__ mixpos)
{
    int i = blockIdx.x, b = blockIdx.y;
    int tid = threadIdx.x;
    if (i == 0)      { if (tid == 0) mixpos[b*L_ + i] = 0;      return; }
    if (i == L_ - 1) { if (tid == 0) mixpos[b*L_ + i] = L_ - 1; return; }

    __shared__ float ks[256*65];    // 65 KB
    __shared__ float sc[512];
    __shared__ float simmax[512];
    __shared__ float qs[64];
    __shared__ float ams[512];
    __shared__ float red[256];
    __shared__ int   redi[256];

    int mb = mix[b];
    for (int u = tid; u < 512; u += 256) { simmax[u] = 0.f; ams[u] = am[mb*L_ + u]; }
    __syncthreads();

    for (int hh = 0; hh < H_; ++hh) {
        if (tid < 64) qs[tid] = q[((size_t)(b*L_ + i)) * D_ + hh*64 + tid];
        __syncthreads();
        for (int c = 0; c < 2; ++c) {
            int j0 = c * 256;
            for (int u = tid; u < 256*64; u += 256) {
                int j = u >> 6, d = u & 63;
                ks[j*65 + d] = k[((size_t)(mb*L_ + j0 + j)) * D_ + hh*64 + d];
            }
            __syncthreads();
            float acc = 0.f;
            #pragma unroll
            for (int d = 0; d < 64; ++d) acc += qs[d] * ks[tid*65 + d];
            sc[j0 + tid] = acc * 0.125f;
            __syncthreads();
        }
        // masked softmax over sc[512], fold max into simmax
        float m0 = ams[tid], m1 = ams[tid + 256];
        float mv0 = sc[tid] * m0, mv1 = sc[tid + 256] * m1;
        red[tid] = fmaxf(mv0, mv1); __syncthreads();
        for (int off = 128; off; off >>= 1) {
            if (tid < off) red[tid] = fmaxf(red[tid], red[tid + off]);
            __syncthreads();
        }
        float mx = red[0];
        __syncthreads();
        float e0 = expf(mv0 - mx) * m0;
        float e1 = expf(mv1 - mx) * m1;
        red[tid] = e0 + e1; __syncthreads();
        for (int off = 128; off; off >>= 1) {
            if (tid < off) red[tid] += red[tid + off];
            __syncthreads();
        }
        float ssum = red[0];
        if (ssum == 0.f) ssum = 1.f;
        float inv = 1.f / ssum;
        __syncthreads();
        simmax[tid]       = fmaxf(simmax[tid],       e0 * inv);
        simmax[tid + 256] = fmaxf(simmax[tid + 256], e1 * inv);
        __syncthreads();
    }

    // masked argmax over interior j in [1, 510]; ties pick larger j
    float bv = -1.f; int bj = 1;
    #pragma unroll
    for (int t = 0; t < 2; ++t) {
        int j = tid + t*256;
        if (j >= 1 && j <= L_ - 2) {
            float vv = simmax[j];
            if (vv > bv || (vv == bv && j > bj)) { bv = vv; bj = j; }
        }
    }
    red[tid] = bv; redi[tid] = bj; __syncthreads();
    for (int off = 128; off; off >>= 1) {
        if (tid < off) {
            float ov = red[tid + off]; int oj = redi[tid + off];
            if (ov > red[tid] || (ov == red[tid] && oj > redi[tid])) {
                red[tid] = ov; redi[tid] = oj;
            }
        }
        __syncthreads();
    }
    if (tid == 0) mixpos[b*L_ + i] = redi[0];
}

// h_new = alpha*h + (1-alpha)*h[mix[b], pos], written to out
__global__ __launch_bounds__(256) void mix_apply_kernel(
    const float* __restrict__ h, const int* __restrict__ mix,
    const int* __restrict__ mixpos, const float* __restrict__ alpha_p,
    float* __restrict__ out)
{
    int row = blockIdx.x;
    int b = row >> 9;
    float alpha = alpha_p[0];
    int mb = mix[b];
    int pos = mixpos[row];
    const float* src = h + ((size_t)(mb*L_ + pos)) * D_;
    const float* cur = h + (size_t)row * D_;
    float* o = out + (size_t)row * D_;
    for (int d = threadIdx.x; d < D_; d += 256)
        o[d] = alpha * cur[d] + (1.f - alpha) * src[d];
}

// mean over sequence, one block per batch
__global__ __launch_bounds__(256) void pool_kernel(
    const float* __restrict__ h, float* __restrict__ pooled)
{
    int b = blockIdx.x;
    for (int d = threadIdx.x; d < D_; d += 256) {
        float s = 0.f;
        for (int ss = 0; ss < L_; ++ss)
            s += h[((size_t)(b*L_ + ss)) * D_ + d];
        pooled[b*D_ + d] = s * (1.f / L_);
    }
}

// ---------------------------------------------------------------------------
extern "C" void kernel_launch(void* const* d_in, const int* in_sizes, int n_in,
                              void* d_out, int out_size, void* d_ws, size_t ws_size,
                              hipStream_t stream)
{
    const int*   ids   = (const int*)  d_in[0];
    const float* am    = (const float*)d_in[1];
    const int*   mix   = (const int*)  d_in[2];
    // d_in[3..5]: is_cls / is_sep / is_normal — derived from position on device
    const float* alpha = (const float*)d_in[6];
    const float* we    = (const float*)d_in[7];
    const float* pe    = (const float*)d_in[8];
    const float* te    = (const float*)d_in[9];
    const float* elnw  = (const float*)d_in[10];
    const float* elnb  = (const float*)d_in[11];
    const float* Wq    = (const float*)d_in[12];
    const float* bq    = (const float*)d_in[13];
    const float* Wk    = (const float*)d_in[14];
    const float* bk    = (const float*)d_in[15];
    const float* Wv    = (const float*)d_in[16];
    const float* bv    = (const float*)d_in[17];
    const float* Wo    = (const float*)d_in[18];
    const float* bo    = (const float*)d_in[19];
    const float* ln1w  = (const float*)d_in[20];
    const float* ln1b  = (const float*)d_in[21];
    const float* Wf1   = (const float*)d_in[22];
    const float* bf1   = (const float*)d_in[23];
    const float* Wf2   = (const float*)d_in[24];
    const float* bf2   = (const float*)d_in[25];
    const float* ln2w  = (const float*)d_in[26];
    const float* ln2b  = (const float*)d_in[27];
    const float* c1w   = (const float*)d_in[28];
    const float* c1b   = (const float*)d_in[29];
    const float* c2w   = (const float*)d_in[30];
    const float* c2b   = (const float*)d_in[31];

    float* ws = (float*)d_ws;
    float* h      = ws;
    float* x1     = ws + ND;
    float* x2     = ws + 2*ND;
    float* x3     = ws + 3*ND;
    float* x4     = ws + 4*ND;
    float* xf     = ws + 5*ND;            // 2048 x 3072 == ND floats
    float* pooled = ws + 6*ND;
    float* t1     = pooled + B_*D_;
    int*   mixpos = (int*)(t1 + B_*128);

    dim3 blk(256);

    // embeddings + LN
    embed_kernel<<<NTOK, blk, 0, stream>>>(ids, we, pe, te, x1);
    ln_kernel<<<NTOK, blk, 0, stream>>>(x1, elnw, elnb, h);

    // ---- mixup (layer 0 weights on pre-mix h) ----
    launch_gemm(h, Wq, bq, nullptr, x1, NTOK, D_, H_*KD_, 0, stream);
    launch_gemm(h, Wk, bk, nullptr, x2, NTOK, D_, H_*KD_, 0, stream);
    mixup_kernel<<<dim3(L_, B_), blk, 0, stream>>>(x1, x2, am, mix, mixpos);
    mix_apply_kernel<<<NTOK, blk, 0, stream>>>(h, mix, mixpos, alpha, x4);
    hipMemcpyAsync(h, x4, ND * sizeof(float), hipMemcpyDeviceToDevice, stream);

    // ---- encoder layers ----
    for (int l = 0; l < NL_; ++l) {
        const float* wq = Wq + (size_t)l * D_ * (H_*KD_);
        const float* wk = Wk + (size_t)l * D_ * (H_*KD_);
        const float* wv = Wv + (size_t)l * D_ * (H_*KD_);
        const float* wo = Wo + (size_t)l * (H_*KD_) * D_;
        const float* wf1 = Wf1 + (size_t)l * D_ * F_;
        const float* wf2 = Wf2 + (size_t)l * F_ * D_;

        launch_gemm(h, wq, bq + (size_t)l*(H_*KD_), nullptr, x1, NTOK, D_, H_*KD_, 0, stream);
        launch_gemm(h, wk, bk + (size_t)l*(H_*KD_), nullptr, x2, NTOK, D_, H_*KD_, 0, stream);
        launch_gemm(h, wv, bv + (size_t)l*(H_*KD_), nullptr, x3, NTOK, D_, H_*KD_, 0, stream);

        attn_kernel<<<dim3(L_/8, H_, B_), blk, 0, stream>>>(x1, x2, x3, am, x4);

        launch_gemm(x4, wo, bo + (size_t)l*D_, h, x1, NTOK, H_*KD_, D_, 0, stream);
        ln_kernel<<<NTOK, blk, 0, stream>>>(x1, ln1w + (size_t)l*D_, ln1b + (size_t)l*D_, h);

        // FF in 4 chunks of 2048 tokens (xf reuse)
        for (int c = 0; c < 4; ++c) {
            const float* hc = h  + (size_t)c * 2048 * D_;
            float*       oc = x2 + (size_t)c * 2048 * D_;
            launch_gemm(hc, wf1, bf1 + (size_t)l*F_, nullptr, xf, 2048, D_, F_, 1, stream);
            launch_gemm(xf, wf2, bf2 + (size_t)l*D_, hc, oc, 2048, F_, D_, 0, stream);
        }
        ln_kernel<<<NTOK, blk, 0, stream>>>(x2, ln2w + (size_t)l*D_, ln2b + (size_t)l*D_, h);
    }

    // ---- pooled head ----
    pool_kernel<<<B_, blk, 0, stream>>>(h, pooled);
    launch_gemm(pooled, c1w, c1b, nullptr, t1, B_, D_, 128, 2, stream);
    launch_gemm(t1, c2w, c2b, nullptr, (float*)d_out, B_, 128, NC_, 0, stream);
}